// Round 2
// baseline (381.472 us; speedup 1.0000x reference)
//
#include <hip/hip_runtime.h>
#include <cstdint>
#include <cstddef>

typedef unsigned short u16;
typedef __attribute__((ext_vector_type(8))) __bf16 bf16x8;
typedef __attribute__((ext_vector_type(8))) unsigned short u16x8;
typedef __attribute__((ext_vector_type(4))) float f32x4;

#define NTOK 197
#define TT   209
#define CDIM 768
#define NH   12
#define HD   64
#define BATCH 64
#define GM (BATCH*TT)   // 13376

__device__ __forceinline__ float bf2f(u16 u){ return __uint_as_float(((unsigned)u)<<16); }
__device__ __forceinline__ u16 f2bf(float f){
  unsigned x = __float_as_uint(f);
  return (u16)((x + 0x7FFFu + ((x>>16)&1u)) >> 16);   // RNE; inputs finite
}

__device__ __forceinline__ void gll16(const void* g, void* l){
  __builtin_amdgcn_global_load_lds((const __attribute__((address_space(1))) void*)g,
                                   (__attribute__((address_space(3))) void*)l,
                                   16, 0, 0);
}

__device__ __forceinline__ float wsum64(float v){
  #pragma unroll
  for (int o = 32; o > 0; o >>= 1) v += __shfl_xor(v, o, 64);
  return v;
}

// ---------------------------------------------------------------- dtype detect
// Interpret first 64K u16 of x as bf16. Genuine bf16 data: max|v| ~ 5.
// f32 data read as bf16: low half-words have random exponents -> max huge.
__global__ __launch_bounds__(256) void detect_kernel(const u16* __restrict__ x, int* flag){
  __shared__ float red[256];
  float mx = 0.f;
  for (int i = threadIdx.x; i < 65536; i += 256) {
    float v = fabsf(bf2f(x[i]));
    if (!(v < 1e30f)) v = 1e30f;     // NaN/Inf -> huge
    mx = fmaxf(mx, v);
  }
  red[threadIdx.x] = mx;
  __syncthreads();
  if (threadIdx.x == 0) {
    float m = 0.f;
    #pragma unroll 8
    for (int i = 0; i < 256; i++) m = fmaxf(m, red[i]);
    *flag = (m < 1e5f) ? 1 : 0;      // 1 = device buffers are bf16
  }
}

// canonicalize input i to bf16 in ws
__global__ __launch_bounds__(256) void convert_kernel(
    const void* __restrict__ in, u16* __restrict__ out, int n, const int* __restrict__ flag){
  const int f = *flag;
  for (int i = blockIdx.x*256 + threadIdx.x; i < n; i += gridDim.x*256) {
    out[i] = f ? ((const u16*)in)[i] : f2bf(((const float*)in)[i]);
  }
}

// ---------------------------------------------------------------- transpose
// in: K x N (row-major) -> out: N x K (row-major). grid (N/64, K/64), 256 thr.
__global__ __launch_bounds__(256) void transpose_kernel(
    const u16* __restrict__ in, u16* __restrict__ out, int K, int N)
{
  __shared__ u16 lds[64][66];
  const int n0 = blockIdx.x*64, k0 = blockIdx.y*64;
  const int c = threadIdx.x & 63, r0 = threadIdx.x >> 6;
  #pragma unroll
  for (int i=0;i<16;i++) {
    int r = i*4 + r0;
    lds[r][c] = in[(size_t)(k0+r)*N + n0 + c];
  }
  __syncthreads();
  #pragma unroll
  for (int i=0;i<16;i++) {
    int r = i*4 + r0;
    out[(size_t)(n0+r)*K + k0 + c] = lds[c][r];
  }
}

// ---------------------------------------------------------------- head token
// one wave per (b,h): mean over N -> 64x768 matvec -> LN(64) -> GELU -> +pos
__global__ __launch_bounds__(64) void ht_kernel(
    const u16* __restrict__ x, const u16* __restrict__ htw, const u16* __restrict__ htb,
    const u16* __restrict__ lng, const u16* __restrict__ lnb, const u16* __restrict__ pos,
    u16* __restrict__ ht)
{
  const int bh = blockIdx.x;
  const int b = bh / NH, h = bh - b*NH;
  const int t = threadIdx.x;
  __shared__ float msh[64];

  const u16* xp = x + (size_t)(b*NTOK)*CDIM + h*HD + t;
  float s = 0.f;
  for (int n = 0; n < NTOK; n++) s += bf2f(xp[(size_t)n*CDIM]);
  msh[t] = s * (1.0f/(float)NTOK);
  __syncthreads();

  float val[NH];
  #pragma unroll
  for (int g=0; g<NH; g++) val[g] = bf2f(htb[g*HD + t]);
  for (int d=0; d<HD; d++) {
    float md = msh[d];
    const u16* wr = htw + (size_t)d*CDIM + t;
    #pragma unroll
    for (int g=0; g<NH; g++) val[g] += md * bf2f(wr[g*HD]);
  }

  const float gam = bf2f(lng[t]), bet = bf2f(lnb[t]);
  #pragma unroll
  for (int g=0; g<NH; g++) {
    float mu = wsum64(val[g]) * (1.0f/(float)HD);
    float dv = val[g] - mu;
    float var = wsum64(dv*dv) * (1.0f/(float)HD);
    float y = dv * rsqrtf(var + 1e-5f) * gam + bet;
    float ge = 0.5f * y * (1.0f + erff(y * 0.70710678118654752f));
    float o = ge + bf2f(pos[h*CDIM + g*HD + t]);
    ht[(size_t)bh*CDIM + g*HD + t] = f2bf(o);
  }
}

// ---------------------------------------------------------------- GEMM
// C = A(13376x768) * B(768xN) + bias, B given transposed (BT: N x 768).
// MODE 0: A rows select x / ht (concat), scatter bf16 into q/k/v (B,H,T,HD).
// MODE 1: A = attn_out, store f32 into po.
// 128x128 tile, BK=32, 4 waves (2x2), global_load_lds staging (m97 pattern).
template<int MODE>
__global__ __launch_bounds__(256) void gemm_kernel(
    const u16* __restrict__ A0, const u16* __restrict__ A1,
    const u16* __restrict__ Bt, const u16* __restrict__ bias,
    u16* __restrict__ qo, u16* __restrict__ ko, u16* __restrict__ vo,
    float* __restrict__ po)
{
  const int tid = threadIdx.x;
  const int lane = tid & 63;
  const int w = tid >> 6;
  const int wm = w >> 1, wn = w & 1;
  const int lr = lane & 15, kg = lane >> 4;
  const int tn = blockIdx.x, tm = blockIdx.y;

  __shared__ __align__(16) u16 As[128*32];
  __shared__ __align__(16) u16 Bs[128*32];

  f32x4 zero = {0.f,0.f,0.f,0.f};
  f32x4 acc[4][4];
  #pragma unroll
  for (int i=0;i<4;i++)
    #pragma unroll
    for (int j=0;j<4;j++) acc[i][j] = zero;

  // per-instruction A/B row pointers (constant across k iterations)
  const u16* garow[2];
  int brow[2];
  #pragma unroll
  for (int i=0;i<2;i++){
    int slot = (i*4 + w)*64 + lane;
    int row = slot >> 2;
    int r = tm*128 + row; if (r > GM-1) r = GM-1;
    if (MODE == 0) {
      int bb = r / TT; int t = r - bb*TT;
      garow[i] = (t < NTOK) ? (A0 + (size_t)(bb*NTOK + t)*CDIM)
                            : (A1 + (size_t)(bb*NH + (t - NTOK))*CDIM);
    } else {
      garow[i] = A0 + (size_t)r*CDIM;
    }
    brow[i] = tn*128 + row;
  }
  const int seg0 = lane & 3;

  for (int k0 = 0; k0 < CDIM; k0 += 32) {
    __syncthreads();
    #pragma unroll
    for (int i=0;i<2;i++){
      gll16(garow[i] + k0 + seg0*8, (void*)&As[(i*4+w)*512]);
      gll16(Bt + (size_t)brow[i]*CDIM + k0 + seg0*8, (void*)&Bs[(i*4+w)*512]);
    }
    asm volatile("s_waitcnt vmcnt(0)" ::: "memory");
    __syncthreads();
    bf16x8 av[4], bv[4];
    #pragma unroll
    for (int mi=0; mi<4; mi++) av[mi] = *(const bf16x8*)&As[(wm*64+mi*16+lr)*32 + kg*8];
    #pragma unroll
    for (int ni=0; ni<4; ni++) bv[ni] = *(const bf16x8*)&Bs[(wn*64+ni*16+lr)*32 + kg*8];
    #pragma unroll
    for (int mi=0; mi<4; mi++)
      #pragma unroll
      for (int ni=0; ni<4; ni++)
        acc[mi][ni] = __builtin_amdgcn_mfma_f32_16x16x32_bf16(av[mi], bv[ni], acc[mi][ni], 0,0,0);
  }

  #pragma unroll
  for (int mi=0; mi<4; mi++){
    const int rb = tm*128 + wm*64 + mi*16 + kg*4;
    #pragma unroll
    for (int ni=0; ni<4; ni++){
      const int c = tn*128 + wn*64 + ni*16 + lr;
      const float bs = bf2f(bias[c]);
      if (MODE == 0) {
        const int which = (c >= 2*CDIM) ? 2 : (c >= CDIM ? 1 : 0);
        const int hh = (c - which*CDIM) >> 6;
        const int dd = c & 63;
        u16* dst = (which==0) ? qo : ((which==1) ? ko : vo);
        #pragma unroll
        for (int j=0;j<4;j++){
          int r = rb + j;
          if (r < GM) {
            int bb = r / TT; int t = r - bb*TT;
            dst[((size_t)(bb*NH + hh)*TT + t)*HD + dd] = f2bf(acc[mi][ni][j] + bs);
          }
        }
      } else {
        #pragma unroll
        for (int j=0;j<4;j++){
          int r = rb + j;
          if (r < GM) po[(size_t)r*CDIM + c] = acc[mi][ni][j] + bs;
        }
      }
    }
  }
}

// ---------------------------------------------------------------- attention
// one block (256 thr) per (b,h). K in LDS [224][72] (zero-padded rows),
// V transposed [64][232] (zero-padded cols), q chunks of 16 rows.
// scores & PV via mfma_16x16x32_bf16; softmax f32 in LDS (stride 225).
__global__ __launch_bounds__(256) void attn_kernel(
    const u16* __restrict__ qb, const u16* __restrict__ kb,
    const u16* __restrict__ vb, u16* __restrict__ ob)
{
  const int bh = blockIdx.x;
  const int b = bh / NH, h = bh - b*NH;
  const int tid = threadIdx.x;
  const int lane = tid & 63;
  const int w = tid >> 6;
  const int lr = lane & 15, kg = lane >> 4;

  __shared__ __align__(16) u16 Kl[224*72];
  __shared__ __align__(16) u16 Vt[64*232];
  __shared__ __align__(16) u16 Ql[16*64];
  __shared__ float S[16*225];
  __shared__ float rsum[16];

  const u16* qg  = qb + (size_t)bh*TT*HD;
  const u16* kgl = kb + (size_t)bh*TT*HD;
  const u16* vgl = vb + (size_t)bh*TT*HD;

  for (int s = tid; s < 224*8; s += 256) {
    int kc = s >> 3, seg = s & 7;
    uint4 val = make_uint4(0,0,0,0);
    if (kc < TT) val = *(const uint4*)&kgl[kc*HD + seg*8];
    *(uint4*)&Kl[kc*72 + seg*8] = val;
  }
  for (int s = tid; s < TT*HD; s += 256) {
    int kc = s >> 6, d = s & 63;
    Vt[d*232 + kc] = vgl[s];
  }
  for (int s = tid; s < 64*15; s += 256) {
    int d = s / 15, kc = TT + (s - (s/15)*15);
    Vt[d*232 + kc] = 0;
  }

  for (int q0 = 0; q0 < TT; q0 += 16) {
    if (tid < 128) {
      int qr = tid >> 3, seg = tid & 7;
      int t = q0 + qr;
      uint4 val = make_uint4(0,0,0,0);
      if (t < TT) val = *(const uint4*)&qg[t*HD + seg*8];
      *(uint4*)&Ql[qr*HD + seg*8] = val;
    }
    __syncthreads();                                   // B1

    // scores: wave w owns k-tiles {w, w+4, ...}
    {
      bf16x8 qa0 = *(const bf16x8*)&Ql[lr*64 + kg*8];
      bf16x8 qa1 = *(const bf16x8*)&Ql[lr*64 + 32 + kg*8];
      for (int kt = w; kt < 14; kt += 4) {
        bf16x8 kf0 = *(const bf16x8*)&Kl[(kt*16+lr)*72 + kg*8];
        bf16x8 kf1 = *(const bf16x8*)&Kl[(kt*16+lr)*72 + 32 + kg*8];
        f32x4 sa = {0.f,0.f,0.f,0.f};
        sa = __builtin_amdgcn_mfma_f32_16x16x32_bf16(qa0, kf0, sa, 0,0,0);
        sa = __builtin_amdgcn_mfma_f32_16x16x32_bf16(qa1, kf1, sa, 0,0,0);
        #pragma unroll
        for (int j=0;j<4;j++)
          S[(kg*4+j)*225 + kt*16 + lr] = sa[j] * 0.125f;
      }
    }
    __syncthreads();                                   // B2

    // softmax: group g = tid>>4 owns row g, lanes tid&15 stride columns
    {
      const int g = tid >> 4, l16 = tid & 15;
      float m = -3.0e38f;
      for (int kc = l16; kc < TT; kc += 16) m = fmaxf(m, S[g*225 + kc]);
      #pragma unroll
      for (int o = 8; o; o >>= 1) m = fmaxf(m, __shfl_xor(m, o, 64));
      float ssum = 0.f;
      for (int kc = l16; kc < 224; kc += 16) {
        float e = (kc < TT) ? __expf(S[g*225 + kc] - m) : 0.f;
        S[g*225 + kc] = e;
        ssum += e;
      }
      #pragma unroll
      for (int o = 8; o; o >>= 1) ssum += __shfl_xor(ssum, o, 64);
      if (l16 == 0) rsum[g] = ssum;
    }
    __syncthreads();                                   // B3

    // PV: wave w owns d-tile w (cols w*16..w*16+15)
    {
      f32x4 oacc = {0.f,0.f,0.f,0.f};
      #pragma unroll
      for (int ks = 0; ks < 7; ks++) {
        const float* ps = &S[lr*225 + ks*32 + kg*8];
        u16x8 pt;
        #pragma unroll
        for (int jj=0;jj<8;jj++) pt[jj] = f2bf(ps[jj]);
        bf16x8 pa = __builtin_bit_cast(bf16x8, pt);
        bf16x8 vf = *(const bf16x8*)&Vt[(w*16+lr)*232 + ks*32 + kg*8];
        oacc = __builtin_amdgcn_mfma_f32_16x16x32_bf16(pa, vf, oacc, 0,0,0);
      }
      #pragma unroll
      for (int j=0;j<4;j++){
        int qrow = kg*4 + j;
        int t = q0 + qrow;
        if (t < TT) {
          float o = oacc[j] / rsum[qrow];
          ob[((size_t)(b*TT + t))*CDIM + h*HD + w*16 + lr] = f2bf(o);
        }
      }
    }
    // next iteration's B1 separates PV's S reads from next scores' S writes
  }
}

// ---------------------------------------------------------------- final
__global__ __launch_bounds__(256) void final_kernel(
    const float* __restrict__ po, void* __restrict__ outv, const int* __restrict__ flag)
{
  const int f = *flag;
  const int total = BATCH*NTOK*CDIM;
  for (int idx = blockIdx.x*256 + threadIdx.x; idx < total; idx += gridDim.x*256) {
    int bn = idx / CDIM;
    int c = idx - bn*CDIM;
    int b = bn / NTOK, n = bn - b*NTOK;
    const float* pb = po + ((size_t)b*TT)*CDIM + c;
    float v;
    if (n == 0) {
      float s = 0.f;
      #pragma unroll
      for (int j=0;j<NH;j++) s += pb[(size_t)(NTOK+j)*CDIM];
      v = pb[0] + s * (1.0f/(float)NH);
    } else {
      v = pb[(size_t)n*CDIM];
    }
    if (f) ((u16*)outv)[idx] = f2bf(v);
    else   ((float*)outv)[idx] = v;
  }
}

// ---------------------------------------------------------------- launch
extern "C" void kernel_launch(void* const* d_in, const int* in_sizes, int n_in,
                              void* d_out, int out_size, void* d_ws, size_t ws_size,
                              hipStream_t stream)
{
  char* ws = (char*)d_ws;
  size_t off = 0;
  auto alloc = [&](size_t bytes)->void* {
    void* p = ws + off; off += (bytes + 255) & ~(size_t)255; return p;
  };

  int* flag = (int*)alloc(256);

  // canonical bf16 copies of all 10 inputs
  u16* cin[10];
  for (int i = 0; i < 10; i++) cin[i] = (u16*)alloc((size_t)in_sizes[i]*2);

  u16* qkvT  = (u16*)alloc((size_t)3*CDIM*CDIM*2);        // 2304 x 768
  u16* projT = (u16*)alloc((size_t)CDIM*CDIM*2);          // 768 x 768
  u16* htb_  = (u16*)alloc((size_t)BATCH*NH*CDIM*2);      // (B*H) x 768
  u16* qb    = (u16*)alloc((size_t)BATCH*NH*TT*HD*2);     // (B,H,T,HD)
  u16* kb    = (u16*)alloc((size_t)BATCH*NH*TT*HD*2);
  u16* vb    = (u16*)alloc((size_t)BATCH*NH*TT*HD*2);
  u16* ao    = (u16*)alloc((size_t)GM*CDIM*2);            // (B*T) x 768
  float* po  = (float*)qb;  // alias: proj f32 out (41.09MB) over dead q+k (41.09MB)

  detect_kernel<<<1, 256, 0, stream>>>((const u16*)d_in[0], flag);
  for (int i = 0; i < 10; i++) {
    int n = in_sizes[i];
    int grid = (n + 255) / 256; if (grid > 1024) grid = 1024;
    convert_kernel<<<grid, 256, 0, stream>>>(d_in[i], cin[i], n, flag);
  }

  const u16* x      = cin[0];
  const u16* qkv_w  = cin[1];
  const u16* qkv_b  = cin[2];
  const u16* proj_w = cin[3];
  const u16* proj_b = cin[4];
  const u16* ht_w   = cin[5];
  const u16* ht_b   = cin[6];
  const u16* ln_g   = cin[7];
  const u16* ln_b   = cin[8];
  const u16* pos    = cin[9];

  transpose_kernel<<<dim3(3*CDIM/64, CDIM/64), 256, 0, stream>>>(qkv_w, qkvT, CDIM, 3*CDIM);
  transpose_kernel<<<dim3(CDIM/64,   CDIM/64), 256, 0, stream>>>(proj_w, projT, CDIM, CDIM);
  ht_kernel<<<BATCH*NH, 64, 0, stream>>>(x, ht_w, ht_b, ln_g, ln_b, pos, htb_);
  gemm_kernel<0><<<dim3(3*CDIM/128, (GM+127)/128), 256, 0, stream>>>(
      x, htb_, qkvT, qkv_b, qb, kb, vb, nullptr);
  attn_kernel<<<BATCH*NH, 256, 0, stream>>>(qb, kb, vb, ao);
  gemm_kernel<1><<<dim3(CDIM/128, (GM+127)/128), 256, 0, stream>>>(
      ao, nullptr, projT, proj_b, nullptr, nullptr, nullptr, po);
  final_kernel<<<2048, 256, 0, stream>>>(po, d_out, flag);
}

// Round 3
// 284.255 us; speedup vs baseline: 1.3420x; 1.3420x over previous
//
#include <hip/hip_runtime.h>
#include <cstdint>
#include <cstddef>

typedef unsigned short u16;
typedef __attribute__((ext_vector_type(8))) __bf16 bf16x8;
typedef __attribute__((ext_vector_type(4))) unsigned short u16x4;
typedef __attribute__((ext_vector_type(4))) float f32x4;

#define NTOK 197
#define TT   209
#define CDIM 768
#define NH   12
#define HD   64
#define BATCH 64
#define GM (BATCH*TT)   // 13376
#define VTP 224         // padded T stride for transposed V

__device__ __forceinline__ float bf2f(u16 u){ return __uint_as_float(((unsigned)u)<<16); }
__device__ __forceinline__ u16 f2bf(float f){
  unsigned x = __float_as_uint(f);
  return (u16)((x + 0x7FFFu + ((x>>16)&1u)) >> 16);   // RNE; inputs finite
}

__device__ __forceinline__ void gll16(const void* g, void* l){
  __builtin_amdgcn_global_load_lds((const __attribute__((address_space(1))) void*)g,
                                   (__attribute__((address_space(3))) void*)l,
                                   16, 0, 0);
}

__device__ __forceinline__ float wsum64(float v){
  #pragma unroll
  for (int o = 32; o > 0; o >>= 1) v += __shfl_xor(v, o, 64);
  return v;
}

// ---------------------------------------------------------------- dtype detect
__global__ __launch_bounds__(256) void detect_kernel(const u16* __restrict__ x, int* flag){
  __shared__ float red[256];
  float mx = 0.f;
  for (int i = threadIdx.x; i < 16384; i += 256) {
    float v = fabsf(bf2f(x[i]));
    if (!(v < 1e30f)) v = 1e30f;     // NaN/Inf -> huge
    mx = fmaxf(mx, v);
  }
  red[threadIdx.x] = mx;
  __syncthreads();
  if (threadIdx.x == 0) {
    float m = 0.f;
    #pragma unroll 8
    for (int i = 0; i < 256; i++) m = fmaxf(m, red[i]);
    *flag = (m < 1e5f) ? 1 : 0;      // 1 = device buffers are bf16
  }
}

// ---------------------------------------------------------------- fused convert
struct CA { const void* in[10]; void* out[10]; int n[10]; };
__global__ __launch_bounds__(256) void convert_all_kernel(CA a, const int* __restrict__ flag){
  const int seg = blockIdx.y;
  const int n = a.n[seg];
  const int f = *flag;
  const int n4 = n >> 2;
  u16* out = (u16*)a.out[seg];
  if (f) {
    const u16x4* in = (const u16x4*)a.in[seg];
    for (int i = blockIdx.x*256 + threadIdx.x; i < n4; i += gridDim.x*256)
      ((u16x4*)out)[i] = in[i];
  } else {
    const f32x4* in = (const f32x4*)a.in[seg];
    for (int i = blockIdx.x*256 + threadIdx.x; i < n4; i += gridDim.x*256){
      f32x4 v = in[i];
      u16x4 o;
      #pragma unroll
      for (int j=0;j<4;j++) o[j] = f2bf(v[j]);
      ((u16x4*)out)[i] = o;
    }
  }
  if (blockIdx.x == 0 && (int)threadIdx.x < (n & 3)) {
    int i = (n4 << 2) + threadIdx.x;
    out[i] = f ? ((const u16*)a.in[seg])[i] : f2bf(((const float*)a.in[seg])[i]);
  }
}

// ---------------------------------------------------------------- transpose
__global__ __launch_bounds__(256) void transpose_kernel(
    const u16* __restrict__ in, u16* __restrict__ out, int K, int N)
{
  __shared__ u16 lds[64][66];
  const int n0 = blockIdx.x*64, k0 = blockIdx.y*64;
  const int c = threadIdx.x & 63, r0 = threadIdx.x >> 6;
  #pragma unroll
  for (int i=0;i<16;i++) {
    int r = i*4 + r0;
    lds[r][c] = in[(size_t)(k0+r)*N + n0 + c];
  }
  __syncthreads();
  #pragma unroll
  for (int i=0;i<16;i++) {
    int r = i*4 + r0;
    out[(size_t)(n0+r)*K + k0 + c] = lds[c][r];
  }
}

// ---------------------------------------------------------------- head token
__global__ __launch_bounds__(64) void ht_kernel(
    const u16* __restrict__ x, const u16* __restrict__ htw, const u16* __restrict__ htb,
    const u16* __restrict__ lng, const u16* __restrict__ lnb, const u16* __restrict__ pos,
    u16* __restrict__ ht)
{
  const int bh = blockIdx.x;
  const int b = bh / NH, h = bh - b*NH;
  const int t = threadIdx.x;
  __shared__ float msh[64];

  const u16* xp = x + (size_t)(b*NTOK)*CDIM + h*HD + t;
  float s = 0.f;
  for (int n = 0; n < NTOK; n++) s += bf2f(xp[(size_t)n*CDIM]);
  msh[t] = s * (1.0f/(float)NTOK);
  __syncthreads();

  float val[NH];
  #pragma unroll
  for (int g=0; g<NH; g++) val[g] = bf2f(htb[g*HD + t]);
  for (int d=0; d<HD; d++) {
    float md = msh[d];
    const u16* wr = htw + (size_t)d*CDIM + t;
    #pragma unroll
    for (int g=0; g<NH; g++) val[g] += md * bf2f(wr[g*HD]);
  }

  const float gam = bf2f(lng[t]), bet = bf2f(lnb[t]);
  #pragma unroll
  for (int g=0; g<NH; g++) {
    float mu = wsum64(val[g]) * (1.0f/(float)HD);
    float dv = val[g] - mu;
    float var = wsum64(dv*dv) * (1.0f/(float)HD);
    float y = dv * rsqrtf(var + 1e-5f) * gam + bet;
    float ge = 0.5f * y * (1.0f + erff(y * 0.70710678118654752f));
    float o = ge + bf2f(pos[h*CDIM + g*HD + t]);
    ht[(size_t)bh*CDIM + g*HD + t] = f2bf(o);
  }
}

// ---------------------------------------------------------------- GEMM
// MODE 0: A rows select x / ht (concat); scatter q/k into (B,H,T,HD), v into
//         (B,H,HD,VTP) transposed. MODE 1: A = attn_out, f32 out into po.
template<int MODE>
__global__ __launch_bounds__(256) void gemm_kernel(
    const u16* __restrict__ A0, const u16* __restrict__ A1,
    const u16* __restrict__ Bt, const u16* __restrict__ bias,
    u16* __restrict__ qo, u16* __restrict__ ko, u16* __restrict__ vo,
    float* __restrict__ po)
{
  const int tid = threadIdx.x;
  const int lane = tid & 63;
  const int w = tid >> 6;
  const int wm = w >> 1, wn = w & 1;
  const int lr = lane & 15, kg = lane >> 4;
  const int tn = blockIdx.x, tm = blockIdx.y;

  __shared__ __align__(16) u16 As[128*32];
  __shared__ __align__(16) u16 Bs[128*32];

  f32x4 zero = {0.f,0.f,0.f,0.f};
  f32x4 acc[4][4];
  #pragma unroll
  for (int i=0;i<4;i++)
    #pragma unroll
    for (int j=0;j<4;j++) acc[i][j] = zero;

  const u16* garow[2];
  int brow[2];
  #pragma unroll
  for (int i=0;i<2;i++){
    int slot = (i*4 + w)*64 + lane;
    int row = slot >> 2;
    int r = tm*128 + row; if (r > GM-1) r = GM-1;
    if (MODE == 0) {
      int bb = r / TT; int t = r - bb*TT;
      garow[i] = (t < NTOK) ? (A0 + (size_t)(bb*NTOK + t)*CDIM)
                            : (A1 + (size_t)(bb*NH + (t - NTOK))*CDIM);
    } else {
      garow[i] = A0 + (size_t)r*CDIM;
    }
    brow[i] = tn*128 + row;
  }
  const int seg0 = lane & 3;

  for (int k0 = 0; k0 < CDIM; k0 += 32) {
    __syncthreads();
    #pragma unroll
    for (int i=0;i<2;i++){
      gll16(garow[i] + k0 + seg0*8, (void*)&As[(i*4+w)*512]);
      gll16(Bt + (size_t)brow[i]*CDIM + k0 + seg0*8, (void*)&Bs[(i*4+w)*512]);
    }
    asm volatile("s_waitcnt vmcnt(0)" ::: "memory");
    __syncthreads();
    bf16x8 av[4], bv[4];
    #pragma unroll
    for (int mi=0; mi<4; mi++) av[mi] = *(const bf16x8*)&As[(wm*64+mi*16+lr)*32 + kg*8];
    #pragma unroll
    for (int ni=0; ni<4; ni++) bv[ni] = *(const bf16x8*)&Bs[(wn*64+ni*16+lr)*32 + kg*8];
    #pragma unroll
    for (int mi=0; mi<4; mi++)
      #pragma unroll
      for (int ni=0; ni<4; ni++)
        acc[mi][ni] = __builtin_amdgcn_mfma_f32_16x16x32_bf16(av[mi], bv[ni], acc[mi][ni], 0,0,0);
  }

  #pragma unroll
  for (int mi=0; mi<4; mi++){
    const int rb = tm*128 + wm*64 + mi*16 + kg*4;
    #pragma unroll
    for (int ni=0; ni<4; ni++){
      const int c = tn*128 + wn*64 + ni*16 + lr;
      const float bs = bf2f(bias[c]);
      if (MODE == 0) {
        const int which = (c >= 2*CDIM) ? 2 : (c >= CDIM ? 1 : 0);
        const int hh = (c - which*CDIM) >> 6;
        const int dd = c & 63;
        #pragma unroll
        for (int j=0;j<4;j++){
          int r = rb + j;
          if (r < GM) {
            int bb = r / TT; int t = r - bb*TT;
            u16 res = f2bf(acc[mi][ni][j] + bs);
            if (which == 2)      vo[((size_t)(bb*NH + hh)*HD + dd)*VTP + t] = res;
            else if (which == 1) ko[((size_t)(bb*NH + hh)*TT + t)*HD + dd] = res;
            else                 qo[((size_t)(bb*NH + hh)*TT + t)*HD + dd] = res;
          }
        }
      } else {
        #pragma unroll
        for (int j=0;j<4;j++){
          int r = rb + j;
          if (r < GM) po[(size_t)r*CDIM + c] = acc[mi][ni][j] + bs;
        }
      }
    }
  }
}

// ---------------------------------------------------------------- attention
// One wave per (b,h, 16-q-row chunk). 14 chunks/head, 10752 waves, 2688 blocks.
// Swapped QK^T: mfma(K,Q) -> lane holds S^T col q=lane&15, rows k=(lane>>4)*4+reg.
// Softmax via 2 shfl_xor across the 4-lane group; P normalized in-register,
// packed bf16 into per-wave subtiled LDS [ks][q][kk], consumed as PV A-frag.
// V read directly from global in (bh, d, t-pad224) layout. No __syncthreads.
__global__ __launch_bounds__(256) void attn_kernel(
    const u16* __restrict__ qb, const u16* __restrict__ kb,
    const u16* __restrict__ vt, u16* __restrict__ ob)
{
  __shared__ __align__(16) u16 P[4][7*16*32];   // 28672 B
  const int tid = threadIdx.x;
  const int lane = tid & 63;
  const int w = tid >> 6;
  const int lr = lane & 15, kg = lane >> 4;

  const int cid = blockIdx.x*4 + w;
  const int bh = cid / 14, ck = cid - bh*14;
  const int b = bh / NH, h = bh - b*NH;
  const int q0 = ck*16;

  const u16* qg = qb + (size_t)bh*TT*HD;
  const u16* kgp = kb + (size_t)bh*TT*HD;
  const u16* vg = vt + (size_t)bh*HD*VTP;

  // Q B-frag: col(q)=lr (clamped), k = kg*8 (+32)
  int qrow = q0 + lr; if (qrow > TT-1) qrow = TT-1;
  const bf16x8 qf0 = *(const bf16x8*)&qg[qrow*HD + kg*8];
  const bf16x8 qf1 = *(const bf16x8*)&qg[qrow*HD + 32 + kg*8];

  // scores S^T over 14 k-tiles
  f32x4 sv[14];
  #pragma unroll
  for (int kt = 0; kt < 14; kt++) {
    int krow = kt*16 + lr; if (krow > TT-1) krow = TT-1;
    const u16* kr = kgp + krow*HD;
    bf16x8 kf0 = *(const bf16x8*)&kr[kg*8];
    bf16x8 kf1 = *(const bf16x8*)&kr[32 + kg*8];
    f32x4 sa = {0.f,0.f,0.f,0.f};
    sa = __builtin_amdgcn_mfma_f32_16x16x32_bf16(kf0, qf0, sa, 0,0,0);
    sa = __builtin_amdgcn_mfma_f32_16x16x32_bf16(kf1, qf1, sa, 0,0,0);
    sv[kt] = sa;
  }

  // scale + mask + row max (row = q = lane&15, spread over 4 lanes)
  float m = -3.0e38f;
  #pragma unroll
  for (int kt = 0; kt < 13; kt++)
    #pragma unroll
    for (int j=0;j<4;j++){ sv[kt][j] *= 0.125f; m = fmaxf(m, sv[kt][j]); }
  #pragma unroll
  for (int j=0;j<4;j++){
    sv[13][j] *= 0.125f;
    if (208 + kg*4 + j < TT) m = fmaxf(m, sv[13][j]);
  }
  m = fmaxf(m, __shfl_xor(m, 16, 64));
  m = fmaxf(m, __shfl_xor(m, 32, 64));

  float ssum = 0.f;
  #pragma unroll
  for (int kt = 0; kt < 13; kt++)
    #pragma unroll
    for (int j=0;j<4;j++){ float e = __expf(sv[kt][j] - m); sv[kt][j] = e; ssum += e; }
  #pragma unroll
  for (int j=0;j<4;j++){
    float e = (208 + kg*4 + j < TT) ? __expf(sv[13][j] - m) : 0.f;
    sv[13][j] = e; ssum += e;
  }
  ssum += __shfl_xor(ssum, 16, 64);
  ssum += __shfl_xor(ssum, 32, 64);
  const float inv = 1.0f / ssum;

  // write normalized P (bf16) into subtiled LDS: elem (q, k) at ks*512 + q*32 + kk
  u16* Pw = &P[w][0];
  #pragma unroll
  for (int kt = 0; kt < 14; kt++) {
    u16x4 pk;
    #pragma unroll
    for (int j=0;j<4;j++) pk[j] = f2bf(sv[kt][j] * inv);
    *(u16x4*)&Pw[(kt>>1)*512 + lr*32 + (kt&1)*16 + kg*4] = pk;
  }

  // PV: A = P (q rows), B = V^T frags from global; D cols d = dt*16+lr, rows q
  f32x4 acc[4];
  #pragma unroll
  for (int dt=0; dt<4; dt++) acc[dt] = (f32x4){0.f,0.f,0.f,0.f};
  #pragma unroll
  for (int ks = 0; ks < 7; ks++) {
    bf16x8 pf = *(const bf16x8*)&Pw[ks*512 + lr*32 + kg*8];
    #pragma unroll
    for (int dt = 0; dt < 4; dt++) {
      bf16x8 vf = *(const bf16x8*)&vg[(dt*16+lr)*VTP + ks*32 + kg*8];
      acc[dt] = __builtin_amdgcn_mfma_f32_16x16x32_bf16(pf, vf, acc[dt], 0,0,0);
    }
  }

  #pragma unroll
  for (int dt = 0; dt < 4; dt++)
    #pragma unroll
    for (int j = 0; j < 4; j++) {
      int tq = q0 + kg*4 + j;
      if (tq < TT)
        ob[((size_t)(b*TT + tq))*CDIM + h*HD + dt*16 + lr] = f2bf(acc[dt][j]);
    }
}

// ---------------------------------------------------------------- final
__global__ __launch_bounds__(256) void final_kernel(
    const float* __restrict__ po, void* __restrict__ outv, const int* __restrict__ flag)
{
  const int f = *flag;
  const int total = BATCH*NTOK*CDIM;
  for (int idx = blockIdx.x*256 + threadIdx.x; idx < total; idx += gridDim.x*256) {
    int bn = idx / CDIM;
    int c = idx - bn*CDIM;
    int b = bn / NTOK, n = bn - b*NTOK;
    const float* pb = po + ((size_t)b*TT)*CDIM + c;
    float v;
    if (n == 0) {
      float s = 0.f;
      #pragma unroll
      for (int j=0;j<NH;j++) s += pb[(size_t)(NTOK+j)*CDIM];
      v = pb[0] + s * (1.0f/(float)NH);
    } else {
      v = pb[(size_t)n*CDIM];
    }
    if (f) ((u16*)outv)[idx] = f2bf(v);
    else   ((float*)outv)[idx] = v;
  }
}

// ---------------------------------------------------------------- launch
extern "C" void kernel_launch(void* const* d_in, const int* in_sizes, int n_in,
                              void* d_out, int out_size, void* d_ws, size_t ws_size,
                              hipStream_t stream)
{
  char* ws = (char*)d_ws;
  size_t off = 0;
  auto alloc = [&](size_t bytes)->void* {
    void* p = ws + off; off += (bytes + 255) & ~(size_t)255; return p;
  };

  int* flag = (int*)alloc(256);

  u16* cin[10];
  for (int i = 0; i < 10; i++) cin[i] = (u16*)alloc((size_t)in_sizes[i]*2);

  u16* qkvT  = (u16*)alloc((size_t)3*CDIM*CDIM*2);        // 2304 x 768
  u16* projT = (u16*)alloc((size_t)CDIM*CDIM*2);          // 768 x 768
  u16* htb_  = (u16*)alloc((size_t)BATCH*NH*CDIM*2);      // (B*H) x 768
  u16* qb    = (u16*)alloc((size_t)BATCH*NH*TT*HD*2);     // (B,H,T,HD)
  u16* kb    = (u16*)alloc((size_t)BATCH*NH*TT*HD*2);
  u16* vb    = (u16*)alloc((size_t)BATCH*NH*HD*VTP*2);    // (B,H,HD,VTP) transposed
  u16* ao    = (u16*)alloc((size_t)GM*CDIM*2);            // (B*T) x 768
  float* po  = (float*)qb;  // alias: proj f32 out (41.09MB) over dead q+k (41.10MB)

  detect_kernel<<<1, 256, 0, stream>>>((const u16*)d_in[0], flag);

  CA ca;
  for (int i = 0; i < 10; i++) { ca.in[i] = d_in[i]; ca.out[i] = cin[i]; ca.n[i] = in_sizes[i]; }
  convert_all_kernel<<<dim3(512, 10), 256, 0, stream>>>(ca, flag);

  const u16* x      = cin[0];
  const u16* qkv_w  = cin[1];
  const u16* qkv_b  = cin[2];
  const u16* proj_w = cin[3];
  const u16* proj_b = cin[4];
  const u16* ht_w   = cin[5];
  const u16* ht_b   = cin[6];
  const u16* ln_g   = cin[7];
  const u16* ln_b   = cin[8];
  const u16* pos    = cin[9];

  transpose_kernel<<<dim3(3*CDIM/64, CDIM/64), 256, 0, stream>>>(qkv_w, qkvT, CDIM, 3*CDIM);
  transpose_kernel<<<dim3(CDIM/64,   CDIM/64), 256, 0, stream>>>(proj_w, projT, CDIM, CDIM);
  ht_kernel<<<BATCH*NH, 64, 0, stream>>>(x, ht_w, ht_b, ln_g, ln_b, pos, htb_);
  gemm_kernel<0><<<dim3(3*CDIM/128, (GM+127)/128), 256, 0, stream>>>(
      x, htb_, qkvT, qkv_b, qb, kb, vb, nullptr);
  attn_kernel<<<(BATCH*NH*14)/4, 256, 0, stream>>>(qb, kb, vb, ao);
  gemm_kernel<1><<<dim3(CDIM/128, (GM+127)/128), 256, 0, stream>>>(
      ao, nullptr, projT, proj_b, nullptr, nullptr, nullptr, po);
  final_kernel<<<2048, 256, 0, stream>>>(po, d_out, flag);
}